// Round 4
// baseline (329.874 us; speedup 1.0000x reference)
//
#include <hip/hip_runtime.h>
#include <hip/hip_bf16.h>
#include <hip/hip_fp16.h>
#include <math.h>

#define EPS 1e-3f
// B=4, S=256, D=256, v=128, e=64, c=192, NH=8, DK=8, DV=8

// ws layout (floats):
// 8192   : cK[64], 8256: dK[64], 8320: cV[64], 8384: dV[64]
// 8448   : q_s [B*D*64]  (relu(q)/sqrt(8))
// 73984  : Pd  [B*D*64]  (V_dst @ We[128:256])
// 139520 : sv  [B*S]     (sum of V_src row)
// 140544 : ssv [B*S]     (sumsq of V_src row)
// 141568 : Qs_k[B*S*64]  (g_in-folded V_src @ Wk[0:128])
// 207104 : Qs_v[B*S*64]
// 272640 : Ps  [B*S*64]  (V_src @ We[0:128])
// 338176 : Wcat bf16, MFMA-fragment-swizzled: idx = ((t*2+c)*64 + lane)*8 + j
//          holds B[k][n], n = t*16+(lane&15), k = c*32+(lane>>4)*8+j   (12288 ushort)
// 344320 : A_t [B,D,S]  (transposed A)  262144 floats
#define WCAT_OFF 338176
#define A_T_OFF  344320
#define E_CHUNK_STRIDE (64 * 256 * 64)   // +64 in s

typedef __attribute__((ext_vector_type(8))) short short8;
typedef __attribute__((ext_vector_type(4))) float floatx4;

__device__ __forceinline__ unsigned short f2bf(float f) {
    __hip_bfloat16 h = __float2bfloat16(f);
    return *reinterpret_cast<unsigned short*>(&h);
}

// Block roles:
//  bid < 1024           : dst path (per (b,d)): LN(V_dst)->q; Pd
//  bid < 2048           : src path (per (b,s)): stats; Qs_k; Qs_v; Ps
//  bid == 2048          : cK/dK/cV/dV
//  bid in [2049, 2057)  : Wcat bf16 fragment-swizzled fill
//  bid in [2057, 2121)  : out2 = 1.0f fill
//  bid in [2121, 2185)  : A[b,s,d] -> A_t[b,d,s] transpose (64x64 tiles)
__global__ __launch_bounds__(256) void pre_kernel(
        const float* __restrict__ V_src, const float* __restrict__ V_dst,
        const float* __restrict__ A,
        const float* __restrict__ g_vd, const float* __restrict__ b_vd,
        const float* __restrict__ g_in, const float* __restrict__ b_in,
        const float* __restrict__ Wq, const float* __restrict__ bq,
        const float* __restrict__ Wk, const float* __restrict__ bk,
        const float* __restrict__ Wv, const float* __restrict__ bv,
        const float* __restrict__ We,
        float* __restrict__ ws, float* __restrict__ out2) {
    int bid = blockIdx.x, tid = threadIdx.x;
    __shared__ float row[128], vn[128], rs1[2], rs2[2];
    __shared__ float tile[64][65];

    if (bid < 1024) {                       // ---- dst path ----
        int blk = bid;
        if (tid < 128) {
            float x = V_dst[blk * 128 + tid];
            row[tid] = x;
            float s1 = x, s2 = x * x;
            #pragma unroll
            for (int o = 1; o <= 32; o <<= 1) { s1 += __shfl_xor(s1, o); s2 += __shfl_xor(s2, o); }
            int w = tid >> 6, l = tid & 63;
            if (l == 0) { rs1[w] = s1; rs2[w] = s2; }
        }
        __syncthreads();
        if (tid < 128) {
            float sum = rs1[0] + rs1[1], ssq = rs2[0] + rs2[1];
            float mu = sum * (1.f / 128.f);
            float var = ssq * (1.f / 128.f) - mu * mu;
            float rsig = rsqrtf(var + EPS);
            vn[tid] = (row[tid] - mu) * rsig * g_vd[tid] + b_vd[tid];
        }
        __syncthreads();
        int n = tid & 63;
        if (tid < 64) {
            float acc = bq[n];
            for (int j = 0; j < 128; j++) acc += vn[j] * Wq[j * 64 + n];
            ws[8448 + blk * 64 + n] = fmaxf(acc, 0.f) * 0.35355339059327373f;
        } else if (tid < 128) {
            float acc = 0.f;
            for (int j = 0; j < 128; j++) acc += row[j] * We[(128 + j) * 64 + n];
            ws[73984 + blk * 64 + n] = acc;
        }
    } else if (bid < 2048) {                // ---- src path ----
        int blk = bid - 1024;
        if (tid < 128) row[tid] = V_src[blk * 128 + tid];
        __syncthreads();
        if (tid < 64) {
            float a = row[tid], b2 = row[tid + 64];
            float s1 = a + b2, s2 = a * a + b2 * b2;
            #pragma unroll
            for (int o = 1; o <= 32; o <<= 1) { s1 += __shfl_xor(s1, o); s2 += __shfl_xor(s2, o); }
            if (tid == 0) { ws[139520 + blk] = s1; ws[140544 + blk] = s2; }
        }
        int g = tid >> 6, n = tid & 63;
        if (g == 0) {
            float acc = 0.f;
            for (int j = 0; j < 128; j++) acc += row[j] * g_in[j] * Wk[j * 64 + n];
            ws[141568 + blk * 64 + n] = acc;
        } else if (g == 1) {
            float acc = 0.f;
            for (int j = 0; j < 128; j++) acc += row[j] * g_in[j] * Wv[j * 64 + n];
            ws[207104 + blk * 64 + n] = acc;
        } else if (g == 2) {
            float acc = 0.f;
            for (int j = 0; j < 128; j++) acc += row[j] * We[j * 64 + n];
            ws[272640 + blk * 64 + n] = acc;
        }
    } else if (bid == 2048) {               // ---- cK/dK/cV/dV ----
        int n = tid & 63;
        if (tid < 64) {
            float c = 0.f, dd = 0.f;
            for (int j = 0; j < 192; j++) { float w = Wk[j * 64 + n]; c += g_in[j] * w; dd += b_in[j] * w; }
            ws[8192 + n] = c; ws[8256 + n] = dd + bk[n];
        } else if (tid < 128) {
            float c = 0.f, dd = 0.f;
            for (int j = 0; j < 192; j++) { float w = Wv[j * 64 + n]; c += g_in[j] * w; dd += b_in[j] * w; }
            ws[8320 + n] = c; ws[8384 + n] = dd + bv[n];
        }
    } else if (bid < 2057) {                // ---- Wcat swizzled fill ----
        unsigned short* wcat = (unsigned short*)(ws + WCAT_OFF);
        int base = (bid - 2049) * 1536;
        for (int ii = tid; ii < 1536; ii += 256) {
            int idx = base + ii;
            int j = idx & 7, l = (idx >> 3) & 63, g = idx >> 9;   // g in [0,24)
            int t = g >> 1, c = g & 1;
            int n = t * 16 + (l & 15);
            int k = c * 32 + (l >> 4) * 8 + j;
            float w;
            if (n < 64)       w = g_in[128 + k] * Wk[(128 + k) * 64 + n];
            else if (n < 128) w = g_in[128 + k] * Wv[(128 + k) * 64 + (n - 64)];
            else              w = We[(256 + k) * 64 + (n - 128)];
            wcat[idx] = f2bf(w);
        }
    } else if (bid < 2121) {                // ---- out2 = 1 ----
        float* p = out2 + (bid - 2057) * 4096;
        float4 one = make_float4(1.f, 1.f, 1.f, 1.f);
        #pragma unroll
        for (int i = 0; i < 4; i++) *(float4*)(p + (i * 256 + tid) * 4) = one;
    } else {                                // ---- A transpose ----
        int tb = bid - 2121;                // 0..63
        int b = tb >> 4, t = tb & 15;
        int si = (t >> 2) * 64, dj = (t & 3) * 64;
        #pragma unroll
        for (int rr = 0; rr < 16; rr++) {
            int idx = rr * 256 + tid; int i = idx >> 6, j = idx & 63;
            tile[i][j] = A[((b * 256 + si + i) << 8) + dj + j];
        }
        __syncthreads();
        #pragma unroll
        for (int rr = 0; rr < 16; rr++) {
            int idx = rr * 256 + tid; int i = idx >> 6, j = idx & 63;
            ws[A_T_OFF + ((b * 256 + dj + i) << 8) + si + j] = tile[j][i];
        }
    }
}

// Fused per (b,d) block. E loaded DIRECTLY into MFMA A-fragment regs (prefetched
// one chunk ahead); B-fragments from LDS (pre-swizzled Wcat, conflict-free b128);
// results parked transposed res_t[n][s] in fp16; per-row softmax-over-heads
// epilogue + E_new write. Single barrier after Wcat copy; main loop barrier-free.
__global__ __launch_bounds__(256, 3) void fused_kernel(
        const float* __restrict__ E,
        const float* __restrict__ V_dst,
        const float* __restrict__ Wo, const float* __restrict__ bo,
        const float* __restrict__ be,
        const float* __restrict__ ws,
        float* __restrict__ out0, float* __restrict__ out1) {
    int blk = blockIdx.x;
    int b = blk >> 8, d = blk & 255;
    int tid = threadIdx.x, wv = tid >> 6, lane = tid & 63;
    int col = lane & 15, quad = lane >> 4;

    __shared__ unsigned short wsm[12288];     // swizzled Wcat frags, 24 KB
    __shared__ __half res_t[192 * 68];        // [n][s], stride 68, 26.1 KB
    __shared__ float ssum[64], sssq[64];
    __shared__ float osm[4][64];
    __shared__ float otot[64];

    // copy swizzled Wcat to LDS (coalesced b128)
    {
        const uint4* src = (const uint4*)(ws + WCAT_OFF);
        uint4* dst = (uint4*)wsm;
        for (int i = tid; i < 1536; i += 256) dst[i] = src[i];
    }

    float cK = ws[8192 + lane], dK = ws[8256 + lane];
    float cV = ws[8320 + lane], dV = ws[8384 + lane];
    float qs  = ws[8448 + blk * 64 + lane];
    float pdv = ws[73984 + blk * 64 + lane];
    float beL = be[lane];
    const float* sv  = ws + 139520 + b * 256;
    const float* ssv = ws + 140544 + b * 256;
    const float* Qsk = ws + 141568 + (size_t)b * 16384;
    const float* Qsv = ws + 207104 + (size_t)b * 16384;
    const float* Ps  = ws + 272640 + (size_t)b * 16384;
    const float* At  = ws + A_T_OFF + (((size_t)(b << 8) + d) << 8);
    __syncthreads();

    // initial E loads: lane = (m=col -> s-row, k = quad*8+j); chunk 0
    const float* ebase = E + (((size_t)((b * 256 + wv * 16 + col) * 256 + d)) << 6) + quad * 8;
    float4 L0 = *(const float4*)(ebase);
    float4 L1 = *(const float4*)(ebase + 4);
    float4 L2 = *(const float4*)(ebase + 32);
    float4 L3 = *(const float4*)(ebase + 36);

    float o_acc = 0.f;
    for (int chunk = 0; chunk < 4; chunk++) {
        int s0 = chunk * 64;
        // ---- convert to A-frags + exact fp32 row stats ----
        short8 a0, a1;
        a0[0]=(short)f2bf(L0.x); a0[1]=(short)f2bf(L0.y); a0[2]=(short)f2bf(L0.z); a0[3]=(short)f2bf(L0.w);
        a0[4]=(short)f2bf(L1.x); a0[5]=(short)f2bf(L1.y); a0[6]=(short)f2bf(L1.z); a0[7]=(short)f2bf(L1.w);
        a1[0]=(short)f2bf(L2.x); a1[1]=(short)f2bf(L2.y); a1[2]=(short)f2bf(L2.z); a1[3]=(short)f2bf(L2.w);
        a1[4]=(short)f2bf(L3.x); a1[5]=(short)f2bf(L3.y); a1[6]=(short)f2bf(L3.z); a1[7]=(short)f2bf(L3.w);
        float p1 = (L0.x + L0.y + L0.z + L0.w) + (L1.x + L1.y + L1.z + L1.w)
                 + (L2.x + L2.y + L2.z + L2.w) + (L3.x + L3.y + L3.z + L3.w);
        float p2 = (L0.x*L0.x + L0.y*L0.y + L0.z*L0.z + L0.w*L0.w)
                 + (L1.x*L1.x + L1.y*L1.y + L1.z*L1.z + L1.w*L1.w)
                 + (L2.x*L2.x + L2.y*L2.y + L2.z*L2.z + L2.w*L2.w)
                 + (L3.x*L3.x + L3.y*L3.y + L3.z*L3.z + L3.w*L3.w);
        // ---- prefetch next chunk's E while we compute ----
        if (chunk < 3) {
            const float* np = ebase + (size_t)(chunk + 1) * E_CHUNK_STRIDE;
            L0 = *(const float4*)(np);
            L1 = *(const float4*)(np + 4);
            L2 = *(const float4*)(np + 32);
            L3 = *(const float4*)(np + 36);
        }
        p1 += __shfl_xor(p1, 16); p2 += __shfl_xor(p2, 16);
        p1 += __shfl_xor(p1, 32); p2 += __shfl_xor(p2, 32);
        if (quad == 0) { ssum[wv * 16 + col] = p1; sssq[wv * 16 + col] = p2; }
        // ---- MFMA: 12 N-tiles, B-frags from LDS (own-lane b128, conflict-free) ----
        #pragma unroll
        for (int t = 0; t < 12; t++) {
            short8 b0 = *(const short8*)(wsm + (t * 2 + 0) * 512 + lane * 8);
            short8 b1 = *(const short8*)(wsm + (t * 2 + 1) * 512 + lane * 8);
            floatx4 acc = {0.f, 0.f, 0.f, 0.f};
            acc = __builtin_amdgcn_mfma_f32_16x16x32_bf16(a0, b0, acc, 0, 0, 0);
            acc = __builtin_amdgcn_mfma_f32_16x16x32_bf16(a1, b1, acc, 0, 0, 0);
            // D[m=quad*4+r][n=t*16+col] -> res_t[n][s=wv*16+quad*4+r], 8B store
            ushort4 hv;
            hv.x = __half_as_ushort(__float2half(acc[0]));
            hv.y = __half_as_ushort(__float2half(acc[1]));
            hv.z = __half_as_ushort(__float2half(acc[2]));
            hv.w = __half_as_ushort(__float2half(acc[3]));
            *(ushort4*)(res_t + (t * 16 + col) * 68 + wv * 16 + quad * 4) = hv;
        }
        // ---- per-row epilogue: softmax over heads + E_new (wave-local) ----
        #pragma unroll 4
        for (int i = 0; i < 16; i++) {
            int sl = wv * 16 + i;
            int s = s0 + sl;
            int row = ((b * 256 + s) << 8) + d;
            float a = At[s];
            float qek = __half2float(res_t[lane * 68 + sl]);
            float qev = __half2float(res_t[(64 + lane) * 68 + sl]);
            float pe  = __half2float(res_t[(128 + lane) * 68 + sl]);
            float mu  = (a * sv[s] + ssum[sl]) * (1.f / 192.f);
            float ex2 = (a * a * ssv[s] + sssq[sl]) * (1.f / 192.f);
            float rsig = rsqrtf(ex2 - mu * mu + EPS);
            float kk = fmaxf(rsig * (a * Qsk[s * 64 + lane] + qek) - rsig * mu * cK + dK, 0.f);
            float vl = fmaxf(rsig * (a * Qsv[s * 64 + lane] + qev) - rsig * mu * cV + dV, 0.f);
            float sc = qs * kk;                       // q pre-scaled by 1/sqrt(8)
            sc += __shfl_xor(sc, 1); sc += __shfl_xor(sc, 2); sc += __shfl_xor(sc, 4);
            // softmax over heads, shift-free (scores bounded far below exp overflow)
            float p = __expf(sc);
            float den = p;
            den += __shfl_xor(den, 8); den += __shfl_xor(den, 16); den += __shfl_xor(den, 32);
            o_acc += p * __builtin_amdgcn_rcpf(den) * vl;
            out1[(size_t)row * 64 + lane] = fmaxf(a * (Ps[s * 64 + lane] + pdv) + pe + beL, 0.f);
        }
    }
    // ---- cross-wave o reduction + Wo epilogue ----
    osm[wv][lane] = o_acc;
    __syncthreads();
    if (tid < 64) otot[tid] = osm[0][tid] + osm[1][tid] + osm[2][tid] + osm[3][tid];
    __syncthreads();
    if (tid < 128) {
        float acc = bo[tid];
        for (int n = 0; n < 64; n++) acc += otot[n] * Wo[n * 128 + tid];
        out0[blk * 128 + tid] = V_dst[blk * 128 + tid] + fmaxf(acc, 0.f);
    }
}

extern "C" void kernel_launch(void* const* d_in, const int* in_sizes, int n_in,
                              void* d_out, int out_size, void* d_ws, size_t ws_size,
                              hipStream_t stream) {
    (void)in_sizes; (void)n_in; (void)out_size; (void)ws_size;
    const float* V_src = (const float*)d_in[0];
    const float* V_dst = (const float*)d_in[1];
    const float* E     = (const float*)d_in[2];
    const float* A     = (const float*)d_in[3];
    const float* g_vd  = (const float*)d_in[4];
    const float* b_vd  = (const float*)d_in[5];
    const float* g_in  = (const float*)d_in[6];
    const float* b_in  = (const float*)d_in[7];
    const float* Wq    = (const float*)d_in[8];
    const float* bq    = (const float*)d_in[9];
    const float* Wk    = (const float*)d_in[10];
    const float* bk    = (const float*)d_in[11];
    const float* Wv    = (const float*)d_in[12];
    const float* bv    = (const float*)d_in[13];
    const float* Wo    = (const float*)d_in[14];
    const float* bo    = (const float*)d_in[15];
    const float* We    = (const float*)d_in[16];
    const float* be    = (const float*)d_in[17];
    float* ws   = (float*)d_ws;
    float* out0 = (float*)d_out;
    float* out1 = out0 + 131072;            // E_new [B,S,D,64]
    float* out2 = out1 + 16777216;          // A_new [B,S,D]

    hipLaunchKernelGGL(pre_kernel,   dim3(2185), dim3(256), 0, stream,
                       V_src, V_dst, A, g_vd, b_vd, g_in, b_in, Wq, bq, Wk, bk, Wv, bv, We, ws, out2);
    hipLaunchKernelGGL(fused_kernel, dim3(1024), dim3(256), 0, stream,
                       E, V_dst, Wo, bo, be, ws, out0, out1);
}

// Round 5
// 302.792 us; speedup vs baseline: 1.0894x; 1.0894x over previous
//
#include <hip/hip_runtime.h>
#include <hip/hip_bf16.h>
#include <hip/hip_fp16.h>
#include <math.h>

#define EPS 1e-3f
// B=4, S=256, D=256, v=128, e=64, c=192, NH=8, DK=8, DV=8

// ws layout (floats):
// 8192   : cK[64], 8256: dK[64], 8320: cV[64], 8384: dV[64]
// 8448   : q_s [B*D*64]  (relu(q)/sqrt(8))
// 73984  : Pd  [B*D*64]  (V_dst @ We[128:256])
// 139520 : sv  [B*S]     (sum of V_src row)
// 140544 : ssv [B*S]     (sumsq of V_src row)
// 141568 : Qs_k[B*S*64]  (g_in-folded V_src @ Wk[0:128])
// 207104 : Qs_v[B*S*64]
// 272640 : Ps  [B*S*64]  (V_src @ We[0:128])
// 338176 : Wcat bf16, MFMA-fragment-swizzled: idx = ((t*2+c)*64 + lane)*8 + j
//          holds B[k][n], n = t*16+(lane&15), k = c*32+(lane>>4)*8+j   (12288 ushort)
// 344320 : A_t [B,D,S]  (transposed A)  262144 floats
#define WCAT_OFF 338176
#define A_T_OFF  344320
#define E_CHUNK_STRIDE (64 * 256 * 64)   // +64 in s

typedef __attribute__((ext_vector_type(8))) short short8;
typedef __attribute__((ext_vector_type(4))) float floatx4;

__device__ __forceinline__ unsigned short f2bf(float f) {
    __hip_bfloat16 h = __float2bfloat16(f);
    return *reinterpret_cast<unsigned short*>(&h);
}

// Block roles:
//  bid < 1024           : dst path (per (b,d)): LN(V_dst)->q; Pd
//  bid < 2048           : src path (per (b,s)): stats; Qs_k; Qs_v; Ps
//  bid == 2048          : cK/dK/cV/dV
//  bid in [2049, 2057)  : Wcat bf16 fragment-swizzled fill
//  bid in [2057, 2121)  : out2 = 1.0f fill
//  bid in [2121, 2185)  : A[b,s,d] -> A_t[b,d,s] transpose (64x64 tiles)
__global__ __launch_bounds__(256) void pre_kernel(
        const float* __restrict__ V_src, const float* __restrict__ V_dst,
        const float* __restrict__ A,
        const float* __restrict__ g_vd, const float* __restrict__ b_vd,
        const float* __restrict__ g_in, const float* __restrict__ b_in,
        const float* __restrict__ Wq, const float* __restrict__ bq,
        const float* __restrict__ Wk, const float* __restrict__ bk,
        const float* __restrict__ Wv, const float* __restrict__ bv,
        const float* __restrict__ We,
        float* __restrict__ ws, float* __restrict__ out2) {
    int bid = blockIdx.x, tid = threadIdx.x;
    __shared__ float row[128], vn[128], rs1[2], rs2[2];
    __shared__ float tile[64][65];

    if (bid < 1024) {                       // ---- dst path ----
        int blk = bid;
        if (tid < 128) {
            float x = V_dst[blk * 128 + tid];
            row[tid] = x;
            float s1 = x, s2 = x * x;
            #pragma unroll
            for (int o = 1; o <= 32; o <<= 1) { s1 += __shfl_xor(s1, o); s2 += __shfl_xor(s2, o); }
            int w = tid >> 6, l = tid & 63;
            if (l == 0) { rs1[w] = s1; rs2[w] = s2; }
        }
        __syncthreads();
        if (tid < 128) {
            float sum = rs1[0] + rs1[1], ssq = rs2[0] + rs2[1];
            float mu = sum * (1.f / 128.f);
            float var = ssq * (1.f / 128.f) - mu * mu;
            float rsig = rsqrtf(var + EPS);
            vn[tid] = (row[tid] - mu) * rsig * g_vd[tid] + b_vd[tid];
        }
        __syncthreads();
        int n = tid & 63;
        if (tid < 64) {
            float acc = bq[n];
            for (int j = 0; j < 128; j++) acc += vn[j] * Wq[j * 64 + n];
            ws[8448 + blk * 64 + n] = fmaxf(acc, 0.f) * 0.35355339059327373f;
        } else if (tid < 128) {
            float acc = 0.f;
            for (int j = 0; j < 128; j++) acc += row[j] * We[(128 + j) * 64 + n];
            ws[73984 + blk * 64 + n] = acc;
        }
    } else if (bid < 2048) {                // ---- src path ----
        int blk = bid - 1024;
        if (tid < 128) row[tid] = V_src[blk * 128 + tid];
        __syncthreads();
        if (tid < 64) {
            float a = row[tid], b2 = row[tid + 64];
            float s1 = a + b2, s2 = a * a + b2 * b2;
            #pragma unroll
            for (int o = 1; o <= 32; o <<= 1) { s1 += __shfl_xor(s1, o); s2 += __shfl_xor(s2, o); }
            if (tid == 0) { ws[139520 + blk] = s1; ws[140544 + blk] = s2; }
        }
        int g = tid >> 6, n = tid & 63;
        if (g == 0) {
            float acc = 0.f;
            for (int j = 0; j < 128; j++) acc += row[j] * g_in[j] * Wk[j * 64 + n];
            ws[141568 + blk * 64 + n] = acc;
        } else if (g == 1) {
            float acc = 0.f;
            for (int j = 0; j < 128; j++) acc += row[j] * g_in[j] * Wv[j * 64 + n];
            ws[207104 + blk * 64 + n] = acc;
        } else if (g == 2) {
            float acc = 0.f;
            for (int j = 0; j < 128; j++) acc += row[j] * We[j * 64 + n];
            ws[272640 + blk * 64 + n] = acc;
        }
    } else if (bid == 2048) {               // ---- cK/dK/cV/dV ----
        int n = tid & 63;
        if (tid < 64) {
            float c = 0.f, dd = 0.f;
            for (int j = 0; j < 192; j++) { float w = Wk[j * 64 + n]; c += g_in[j] * w; dd += b_in[j] * w; }
            ws[8192 + n] = c; ws[8256 + n] = dd + bk[n];
        } else if (tid < 128) {
            float c = 0.f, dd = 0.f;
            for (int j = 0; j < 192; j++) { float w = Wv[j * 64 + n]; c += g_in[j] * w; dd += b_in[j] * w; }
            ws[8320 + n] = c; ws[8384 + n] = dd + bv[n];
        }
    } else if (bid < 2057) {                // ---- Wcat swizzled fill ----
        unsigned short* wcat = (unsigned short*)(ws + WCAT_OFF);
        int base = (bid - 2049) * 1536;
        for (int ii = tid; ii < 1536; ii += 256) {
            int idx = base + ii;
            int j = idx & 7, l = (idx >> 3) & 63, g = idx >> 9;   // g in [0,24)
            int t = g >> 1, c = g & 1;
            int n = t * 16 + (l & 15);
            int k = c * 32 + (l >> 4) * 8 + j;
            float w;
            if (n < 64)       w = g_in[128 + k] * Wk[(128 + k) * 64 + n];
            else if (n < 128) w = g_in[128 + k] * Wv[(128 + k) * 64 + (n - 64)];
            else              w = We[(256 + k) * 64 + (n - 128)];
            wcat[idx] = f2bf(w);
        }
    } else if (bid < 2121) {                // ---- out2 = 1 ----
        float* p = out2 + (bid - 2057) * 4096;
        float4 one = make_float4(1.f, 1.f, 1.f, 1.f);
        #pragma unroll
        for (int i = 0; i < 4; i++) *(float4*)(p + (i * 256 + tid) * 4) = one;
    } else {                                // ---- A transpose ----
        int tb = bid - 2121;                // 0..63
        int b = tb >> 4, t = tb & 15;
        int si = (t >> 2) * 64, dj = (t & 3) * 64;
        #pragma unroll
        for (int rr = 0; rr < 16; rr++) {
            int idx = rr * 256 + tid; int i = idx >> 6, j = idx & 63;
            tile[i][j] = A[((b * 256 + si + i) << 8) + dj + j];
        }
        __syncthreads();
        #pragma unroll
        for (int rr = 0; rr < 16; rr++) {
            int idx = rr * 256 + tid; int i = idx >> 6, j = idx & 63;
            ws[A_T_OFF + ((b * 256 + dj + i) << 8) + si + j] = tile[j][i];
        }
    }
}

// Fused per (b,d) block. E loaded directly into MFMA A-frags (prefetch 1 chunk).
// Softmax-over-heads done ENTIRELY in MFMA register layout:
//   D-layout: n = 16t + col, s_local = quad*4 + r.  head = n>>3 = 2t + (col>=8),
//   x = col&7.  Score sum over x = xor 1/2/4 shuffles; den over heads = sum over
//   the 4 K-tile regs + one xor-8; PV weight sits in the SAME lane/reg as vl ->
//   o accumulation is pure per-lane FMA. Only E-tile results go through LDS
//   (fp16, [s][n] stride 66) for the coalesced E_new store.
__global__ __launch_bounds__(256, 4) void fused_kernel(
        const float* __restrict__ E,
        const float* __restrict__ V_dst,
        const float* __restrict__ Wo, const float* __restrict__ bo,
        const float* __restrict__ be,
        const float* __restrict__ ws,
        float* __restrict__ out0, float* __restrict__ out1) {
    int blk = blockIdx.x;
    int b = blk >> 8, d = blk & 255;
    int tid = threadIdx.x, wv = tid >> 6, lane = tid & 63;
    int col = lane & 15, quad = lane >> 4;

    __shared__ unsigned short wsm[12288];     // swizzled Wcat frags, 24 KB
    __shared__ unsigned short res16[64 * 66]; // E-tile results [s_loc][n] fp16, 8.25 KB
    __shared__ float ssum[64], sssq[64];
    __shared__ float osm[4][64];
    __shared__ float otot[64];

    // copy swizzled Wcat to LDS (coalesced b128)
    {
        const uint4* src = (const uint4*)(ws + WCAT_OFF);
        uint4* dst = (uint4*)wsm;
        for (int i = tid; i < 1536; i += 256) dst[i] = src[i];
    }

    // lane = n constants (E_new epilogue + final Wo path)
    float pdv = ws[73984 + blk * 64 + lane];
    float beL = be[lane];
    // register-layout constants at n = 16t + col
    float cK[4], dK[4], cV[4], dV[4], qsr[4];
    #pragma unroll
    for (int t = 0; t < 4; t++) {
        cK[t]  = ws[8192 + 16 * t + col];
        dK[t]  = ws[8256 + 16 * t + col];
        cV[t]  = ws[8320 + 16 * t + col];
        dV[t]  = ws[8384 + 16 * t + col];
        qsr[t] = ws[8448 + blk * 64 + 16 * t + col];
    }
    const float* sv  = ws + 139520 + b * 256;
    const float* ssv = ws + 140544 + b * 256;
    const float* Qsk = ws + 141568 + (size_t)b * 16384;
    const float* Qsv = ws + 207104 + (size_t)b * 16384;
    const float* Ps  = ws + 272640 + (size_t)b * 16384;
    const float* At  = ws + A_T_OFF + (((size_t)(b << 8) + d) << 8);
    __syncthreads();

    // E in A-frag layout: A-row m = col (s_loc = wv*16+col), k = quad*8 + j
    const float* ebase = E + (((size_t)((b * 256 + wv * 16 + col) * 256 + d)) << 6) + quad * 8;
    float4 L0 = *(const float4*)(ebase);
    float4 L1 = *(const float4*)(ebase + 4);
    float4 L2 = *(const float4*)(ebase + 32);
    float4 L3 = *(const float4*)(ebase + 36);

    float o_acc[4][4];
    #pragma unroll
    for (int t = 0; t < 4; t++)
        #pragma unroll
        for (int r = 0; r < 4; r++) o_acc[t][r] = 0.f;

    for (int chunk = 0; chunk < 4; chunk++) {
        int s0 = chunk * 64;
        // ---- convert to A-frags + exact fp32 row stats ----
        short8 a0, a1;
        a0[0]=(short)f2bf(L0.x); a0[1]=(short)f2bf(L0.y); a0[2]=(short)f2bf(L0.z); a0[3]=(short)f2bf(L0.w);
        a0[4]=(short)f2bf(L1.x); a0[5]=(short)f2bf(L1.y); a0[6]=(short)f2bf(L1.z); a0[7]=(short)f2bf(L1.w);
        a1[0]=(short)f2bf(L2.x); a1[1]=(short)f2bf(L2.y); a1[2]=(short)f2bf(L2.z); a1[3]=(short)f2bf(L2.w);
        a1[4]=(short)f2bf(L3.x); a1[5]=(short)f2bf(L3.y); a1[6]=(short)f2bf(L3.z); a1[7]=(short)f2bf(L3.w);
        float p1 = (L0.x + L0.y + L0.z + L0.w) + (L1.x + L1.y + L1.z + L1.w)
                 + (L2.x + L2.y + L2.z + L2.w) + (L3.x + L3.y + L3.z + L3.w);
        float p2 = (L0.x*L0.x + L0.y*L0.y + L0.z*L0.z + L0.w*L0.w)
                 + (L1.x*L1.x + L1.y*L1.y + L1.z*L1.z + L1.w*L1.w)
                 + (L2.x*L2.x + L2.y*L2.y + L2.z*L2.z + L2.w*L2.w)
                 + (L3.x*L3.x + L3.y*L3.y + L3.z*L3.z + L3.w*L3.w);
        // ---- prefetch next chunk's E ----
        if (chunk < 3) {
            const float* np = ebase + (size_t)(chunk + 1) * E_CHUNK_STRIDE;
            L0 = *(const float4*)(np);
            L1 = *(const float4*)(np + 4);
            L2 = *(const float4*)(np + 32);
            L3 = *(const float4*)(np + 36);
        }
        p1 += __shfl_xor(p1, 16); p2 += __shfl_xor(p2, 16);
        p1 += __shfl_xor(p1, 32); p2 += __shfl_xor(p2, 32);
        if (quad == 0) { ssum[wv * 16 + col] = p1; sssq[wv * 16 + col] = p2; }

        // ---- issue Qsk gathers early (consumed in K phase) ----
        float kga[4][4];
        #pragma unroll
        for (int t = 0; t < 4; t++)
            #pragma unroll
            for (int r = 0; r < 4; r++)
                kga[t][r] = Qsk[(s0 + wv * 16 + quad * 4 + r) * 64 + 16 * t + col];

        // ---- E tiles -> res16 (fp16, [s][n] stride 66) ----
        #pragma unroll
        for (int t = 0; t < 4; t++) {
            short8 b0 = *(const short8*)(wsm + ((8 + t) * 2 + 0) * 512 + lane * 8);
            short8 b1 = *(const short8*)(wsm + ((8 + t) * 2 + 1) * 512 + lane * 8);
            floatx4 acc = {0.f, 0.f, 0.f, 0.f};
            acc = __builtin_amdgcn_mfma_f32_16x16x32_bf16(a0, b0, acc, 0, 0, 0);
            acc = __builtin_amdgcn_mfma_f32_16x16x32_bf16(a1, b1, acc, 0, 0, 0);
            #pragma unroll
            for (int r = 0; r < 4; r++)
                res16[(wv * 16 + quad * 4 + r) * 66 + 16 * t + col] =
                    __half_as_ushort(__float2half(acc[r]));
        }
        // ---- E_new epilogue (lane = n; hides kga latency) ----
        #pragma unroll 4
        for (int i = 0; i < 16; i++) {
            int sl = wv * 16 + i;
            int s = s0 + sl;
            int row = ((b * 256 + s) << 8) + d;
            float a = At[s];
            float pe = __half2float(__ushort_as_half(res16[sl * 66 + lane]));
            float ps = Ps[s * 64 + lane];
            out1[(size_t)row * 64 + lane] = fmaxf(a * (ps + pdv) + pe + beL, 0.f);
        }

        // ---- per-s-row scalars (register layout: s = s0 + wv*16 + quad*4 + r) ----
        float mu[4], rs[4], av[4];
        #pragma unroll
        for (int r = 0; r < 4; r++) {
            int sl = wv * 16 + quad * 4 + r;
            int s = s0 + sl;
            av[r] = At[s];
            float m  = (av[r] * sv[s] + ssum[sl]) * (1.f / 192.f);
            float e2 = (av[r] * av[r] * ssv[s] + sssq[sl]) * (1.f / 192.f);
            mu[r] = m;
            rs[r] = rsqrtf(e2 - m * m + EPS);
        }

        // ---- K tiles -> kk -> scores (register-layout softmax) ----
        float sc[4][4];
        #pragma unroll
        for (int t = 0; t < 4; t++) {
            short8 b0 = *(const short8*)(wsm + (t * 2 + 0) * 512 + lane * 8);
            short8 b1 = *(const short8*)(wsm + (t * 2 + 1) * 512 + lane * 8);
            floatx4 acc = {0.f, 0.f, 0.f, 0.f};
            acc = __builtin_amdgcn_mfma_f32_16x16x32_bf16(a0, b0, acc, 0, 0, 0);
            acc = __builtin_amdgcn_mfma_f32_16x16x32_bf16(a1, b1, acc, 0, 0, 0);
            #pragma unroll
            for (int r = 0; r < 4; r++) {
                float kk = fmaxf(rs[r] * (av[r] * kga[t][r] + acc[r])
                                 - rs[r] * mu[r] * cK[t] + dK[t], 0.f);
                sc[t][r] = qsr[t] * kk;     // q pre-scaled by 1/sqrt(8)
            }
        }
        // score sum over x (8 lanes within head): xor 1,2,4
        #pragma unroll
        for (int t = 0; t < 4; t++)
            #pragma unroll
            for (int r = 0; r < 4; r++) {
                float v = sc[t][r];
                v += __shfl_xor(v, 1); v += __shfl_xor(v, 2); v += __shfl_xor(v, 4);
                sc[t][r] = v;
            }
        // ---- issue Qsv gathers (consumed in V phase) ----
        float vga[4][4];
        #pragma unroll
        for (int t = 0; t < 4; t++)
            #pragma unroll
            for (int r = 0; r < 4; r++)
                vga[t][r] = Qsv[(s0 + wv * 16 + quad * 4 + r) * 64 + 16 * t + col];
        // softmax over heads: lane holds heads {2t + (col>=8)}; other parity via xor 8
        float pw[4][4], rd[4];
        #pragma unroll
        for (int r = 0; r < 4; r++) {
            float dh = 0.f;
            #pragma unroll
            for (int t = 0; t < 4; t++) { pw[t][r] = __expf(sc[t][r]); dh += pw[t][r]; }
            float den = dh + __shfl_xor(dh, 8);
            rd[r] = __builtin_amdgcn_rcpf(den);
        }
        // ---- V tiles -> vl -> o accumulation (pure per-lane FMA) ----
        #pragma unroll
        for (int t = 0; t < 4; t++) {
            short8 b0 = *(const short8*)(wsm + ((4 + t) * 2 + 0) * 512 + lane * 8);
            short8 b1 = *(const short8*)(wsm + ((4 + t) * 2 + 1) * 512 + lane * 8);
            floatx4 acc = {0.f, 0.f, 0.f, 0.f};
            acc = __builtin_amdgcn_mfma_f32_16x16x32_bf16(a0, b0, acc, 0, 0, 0);
            acc = __builtin_amdgcn_mfma_f32_16x16x32_bf16(a1, b1, acc, 0, 0, 0);
            #pragma unroll
            for (int r = 0; r < 4; r++) {
                float vl = fmaxf(rs[r] * (av[r] * vga[t][r] + acc[r])
                                 - rs[r] * mu[r] * cV[t] + dV[t], 0.f);
                o_acc[t][r] += pw[t][r] * rd[r] * vl;
            }
        }
    }
    // ---- o reduction: in-lane over r, cross-quad xor16/32, cross-wave via LDS ----
    #pragma unroll
    for (int t = 0; t < 4; t++) {
        float x = o_acc[t][0] + o_acc[t][1] + o_acc[t][2] + o_acc[t][3];
        x += __shfl_xor(x, 16); x += __shfl_xor(x, 32);
        if (quad == 0) osm[wv][t * 16 + col] = x;
    }
    __syncthreads();
    if (tid < 64) otot[tid] = osm[0][tid] + osm[1][tid] + osm[2][tid] + osm[3][tid];
    __syncthreads();
    if (tid < 128) {
        float acc = bo[tid];
        for (int n = 0; n < 64; n++) acc += otot[n] * Wo[n * 128 + tid];
        out0[blk * 128 + tid] = V_dst[blk * 128 + tid] + fmaxf(acc, 0.f);
    }
}

extern "C" void kernel_launch(void* const* d_in, const int* in_sizes, int n_in,
                              void* d_out, int out_size, void* d_ws, size_t ws_size,
                              hipStream_t stream) {
    (void)in_sizes; (void)n_in; (void)out_size; (void)ws_size;
    const float* V_src = (const float*)d_in[0];
    const float* V_dst = (const float*)d_in[1];
    const float* E     = (const float*)d_in[2];
    const float* A     = (const float*)d_in[3];
    const float* g_vd  = (const float*)d_in[4];
    const float* b_vd  = (const float*)d_in[5];
    const float* g_in  = (const float*)d_in[6];
    const float* b_in  = (const float*)d_in[7];
    const float* Wq    = (const float*)d_in[8];
    const float* bq    = (const float*)d_in[9];
    const float* Wk    = (const float*)d_in[10];
    const float* bk    = (const float*)d_in[11];
    const float* Wv    = (const float*)d_in[12];
    const float* bv    = (const float*)d_in[13];
    const float* Wo    = (const float*)d_in[14];
    const float* bo    = (const float*)d_in[15];
    const float* We    = (const float*)d_in[16];
    const float* be    = (const float*)d_in[17];
    float* ws   = (float*)d_ws;
    float* out0 = (float*)d_out;
    float* out1 = out0 + 131072;            // E_new [B,S,D,64]
    float* out2 = out1 + 16777216;          // A_new [B,S,D]

    hipLaunchKernelGGL(pre_kernel,   dim3(2185), dim3(256), 0, stream,
                       V_src, V_dst, A, g_vd, b_vd, g_in, b_in, Wq, bq, Wk, bk, Wv, bv, We, ws, out2);
    hipLaunchKernelGGL(fused_kernel, dim3(1024), dim3(256), 0, stream,
                       E, V_dst, Wo, bo, be, ws, out0, out1);
}